// Round 1
// baseline (694.045 us; speedup 1.0000x reference)
//
#include <hip/hip_runtime.h>

typedef __attribute__((ext_vector_type(4))) float f32x4;
typedef __attribute__((ext_vector_type(8))) short short8;
typedef __attribute__((ext_vector_type(4))) unsigned short u16x4;
typedef __attribute__((ext_vector_type(8))) unsigned short u16x8;

#define MFMA(a, b, c) __builtin_amdgcn_mfma_f32_16x16x32_bf16(a, b, c, 0, 0, 0)

__device__ inline unsigned short f2bf(float f) {
    unsigned int u = __float_as_uint(f);
    u += 0x7fffu + ((u >> 16) & 1u);   // RNE
    return (unsigned short)(u >> 16);
}

// ---------------------------------------------------------------------------
// fp32 -> bf16 elementwise (weights)
__global__ __launch_bounds__(256) void cvt_kernel(const float* __restrict__ in,
                                                  unsigned short* __restrict__ out, int n4) {
    int i = blockIdx.x * 256 + threadIdx.x;
    if (i < n4) {
        f32x4 v = *(const f32x4*)(in + (long long)i * 4);
        u16x4 o;
#pragma unroll
        for (int j = 0; j < 4; j++) o[j] = f2bf(v[j]);
        *(u16x4*)&out[(long long)i * 4] = o;
    }
}

// ---------------------------------------------------------------------------
// LayerNorm: fp32 [rows,1024] -> bf16 out. One block per row.
__global__ __launch_bounds__(256) void ln_kernel(const float* __restrict__ x,
                                                 const float* __restrict__ g,
                                                 const float* __restrict__ be,
                                                 unsigned short* __restrict__ out) {
    const int row = blockIdx.x, tid = threadIdx.x;
    const float* px = x + (long long)row * 1024;
    f32x4 v = *(const f32x4*)(px + tid * 4);
    float s = v[0] + v[1] + v[2] + v[3];
    float q = v[0] * v[0] + v[1] * v[1] + v[2] * v[2] + v[3] * v[3];
#pragma unroll
    for (int o = 32; o; o >>= 1) { s += __shfl_xor(s, o); q += __shfl_xor(q, o); }
    __shared__ float sm[10];
    const int lane = tid & 63, wid = tid >> 6;
    if (lane == 0) { sm[wid] = s; sm[4 + wid] = q; }
    __syncthreads();
    if (tid == 0) {
        float ts = sm[0] + sm[1] + sm[2] + sm[3];
        float tq = sm[4] + sm[5] + sm[6] + sm[7];
        float mean = ts * (1.f / 1024.f);
        float var = tq * (1.f / 1024.f) - mean * mean;
        sm[8] = mean; sm[9] = rsqrtf(var + 1e-5f);
    }
    __syncthreads();
    float mean = sm[8], rs = sm[9];
    f32x4 gg = *(const f32x4*)(g + tid * 4);
    f32x4 bb = *(const f32x4*)(be + tid * 4);
    u16x4 o;
#pragma unroll
    for (int i = 0; i < 4; i++) o[i] = f2bf((v[i] - mean) * rs * gg[i] + bb[i]);
    *(u16x4*)&out[(long long)row * 1024 + tid * 4] = o;
}

// ---------------------------------------------------------------------------
// Causal softmax over row [0..t], writes bf16 probs IN-PLACE over the fp32 row
// (first half of each 8KB row). Zeros for s>t. grid (T, B).
__global__ __launch_bounds__(256) void softmax_kernel(float* __restrict__ S) {
    const int T = 2048;
    const int t = blockIdx.x, b = blockIdx.y, tid = threadIdx.x;
    float* row = S + ((long long)b * T + t) * T;
    const int base = tid * 8;
    f32x4 v0 = *(const f32x4*)(row + base);
    f32x4 v1 = *(const f32x4*)(row + base + 4);
    float mx = -1e30f;
#pragma unroll
    for (int i = 0; i < 4; i++) {
        if (base + i <= t)     mx = fmaxf(mx, v0[i]);
        if (base + 4 + i <= t) mx = fmaxf(mx, v1[i]);
    }
#pragma unroll
    for (int o = 32; o; o >>= 1) mx = fmaxf(mx, __shfl_xor(mx, o));
    __shared__ float sm[10];
    const int lane = tid & 63, wid = tid >> 6;
    if (lane == 0) sm[wid] = mx;
    __syncthreads();
    if (tid == 0) sm[8] = fmaxf(fmaxf(sm[0], sm[1]), fmaxf(sm[2], sm[3]));
    __syncthreads();
    float M = sm[8];
    float e[8]; float s = 0.f;
#pragma unroll
    for (int i = 0; i < 4; i++) {
        e[i]     = (base + i <= t)     ? __expf(v0[i] - M) : 0.f;
        e[4 + i] = (base + 4 + i <= t) ? __expf(v1[i] - M) : 0.f;
        s += e[i] + e[4 + i];
    }
#pragma unroll
    for (int o = 32; o; o >>= 1) s += __shfl_xor(s, o);
    if (lane == 0) sm[4 + wid] = s;
    __syncthreads();
    if (tid == 0) sm[9] = 1.f / (sm[4] + sm[5] + sm[6] + sm[7]);
    __syncthreads();
    float inv = sm[9];
    unsigned short* P = (unsigned short*)row;
    u16x8 o;
#pragma unroll
    for (int i = 0; i < 8; i++) o[i] = f2bf(e[i] * inv);
    *(u16x8*)&P[base] = o;   // safe: all loads done before barriers above
}

// ---------------------------------------------------------------------------
// GEMM: Y[M,N] = A[M,K](bf16) @ B[N,K]^T(bf16) (+bias) ; both operands K-contig.
// 64x64 tile, 4 waves (2x2), each wave 2x2 of 16x16x32 MFMA frags.
// MODE: 0 fp32 out | 1 fp32 out + residual | 2 bf16 out (*scale after bias)
//       3 bf16 out TRANSPOSED (out[n*ldo+m]) | 4 fp32 AND bf16 | 5 bf16 GELU
// flags: bit0 = causal block skip (n0>m0), bit1 = K limited to m0+64
template <int MODE>
__global__ __launch_bounds__(256) void gemm_bt(
    const unsigned short* __restrict__ A, int lda, long long sA,
    const unsigned short* __restrict__ Bw, int ldb, long long sB,
    const float* __restrict__ bias,
    const float* __restrict__ resid, long long sR,
    float* __restrict__ outf, unsigned short* __restrict__ outb,
    int ldo, long long sO, int K, float scale, int flags) {
    const int m0 = blockIdx.y * 64, n0 = blockIdx.x * 64;
    if ((flags & 1) && n0 > m0) return;
    const int bz = blockIdx.z;
    A += (long long)bz * sA; Bw += (long long)bz * sB;
    if (resid) resid += (long long)bz * sR;
    if (outf) outf += (long long)bz * sO;
    if (outb) outb += (long long)bz * sO;
    const int Keff = (flags & 2) ? (m0 + 64 < K ? m0 + 64 : K) : K;

    __shared__ __align__(16) unsigned short As[64 * 40];
    __shared__ __align__(16) unsigned short Bs[64 * 40];
    const int tid = threadIdx.x;
    const int lr = tid >> 2, lc = (tid & 3) * 8;
    const unsigned short* ga = A + (long long)(m0 + lr) * lda + lc;
    const unsigned short* gb = Bw + (long long)(n0 + lr) * ldb + lc;
    const int lane = tid & 63, wid = tid >> 6;
    const int wm = (wid >> 1) * 32, wn = (wid & 1) * 32;
    const int fr = lane & 15, fk = (lane >> 4) * 8;

    f32x4 acc[2][2] = {};
    for (int k0 = 0; k0 < Keff; k0 += 32) {
        *(u16x8*)&As[lr * 40 + lc] = *(const u16x8*)(ga + k0);
        *(u16x8*)&Bs[lr * 40 + lc] = *(const u16x8*)(gb + k0);
        __syncthreads();
        short8 a0 = *(const short8*)&As[(wm + fr) * 40 + fk];
        short8 a1 = *(const short8*)&As[(wm + 16 + fr) * 40 + fk];
        short8 b0 = *(const short8*)&Bs[(wn + fr) * 40 + fk];
        short8 b1 = *(const short8*)&Bs[(wn + 16 + fr) * 40 + fk];
        acc[0][0] = MFMA(a0, b0, acc[0][0]);
        acc[0][1] = MFMA(a0, b1, acc[0][1]);
        acc[1][0] = MFMA(a1, b0, acc[1][0]);
        acc[1][1] = MFMA(a1, b1, acc[1][1]);
        __syncthreads();
    }

    const int cc = lane & 15, rr = (lane >> 4) * 4;
#pragma unroll
    for (int fm = 0; fm < 2; fm++)
#pragma unroll
        for (int fn = 0; fn < 2; fn++) {
            f32x4 av = acc[fm][fn];
            int colg = n0 + wn + fn * 16 + cc;
            int rowg0 = m0 + wm + fm * 16 + rr;
            float bv = bias ? bias[colg] : 0.f;
            if (MODE == 3) {
                u16x4 o;
#pragma unroll
                for (int i = 0; i < 4; i++) o[i] = f2bf((av[i] + bv) * scale);
                *(u16x4*)&outb[(long long)colg * ldo + rowg0] = o;
            } else {
#pragma unroll
                for (int i = 0; i < 4; i++) {
                    float v = av[i] + bv;
                    long long idx = (long long)(rowg0 + i) * ldo + colg;
                    if (MODE == 0) outf[idx] = v;
                    if (MODE == 1) outf[idx] = v + resid[idx];
                    if (MODE == 2) outb[idx] = f2bf(v * scale);
                    if (MODE == 4) { outf[idx] = v; outb[idx] = f2bf(v); }
                    if (MODE == 5) outb[idx] = f2bf(0.5f * v * (1.f + erff(v * 0.70710678f)));
                }
            }
        }
}

// ---------------------------------------------------------------------------
extern "C" void kernel_launch(void* const* d_in, const int* in_sizes, int n_in,
                              void* d_out, int out_size, void* d_ws, size_t ws_size,
                              hipStream_t stream) {
    const float* x      = (const float*)d_in[0];
    const float* g1     = (const float*)d_in[1];
    const float* be1    = (const float*)d_in[2];
    const float* b_lin1 = (const float*)d_in[4];
    const float* bq     = (const float*)d_in[6];
    const float* bk     = (const float*)d_in[8];
    const float* bv     = (const float*)d_in[10];
    const float* b_lin2 = (const float*)d_in[12];
    const float* g2     = (const float*)d_in[13];
    const float* be2    = (const float*)d_in[14];
    const float* b_ff1  = (const float*)d_in[16];
    const float* b_ff2  = (const float*)d_in[18];

    const long long MB = 1024LL * 1024LL;
    char* ws = (char*)d_ws;
    // lifetime-overlapped layout (194MB total)
    unsigned short* xn1 = (unsigned short*)(ws + 0);        // 16MB, dead after lin1
    unsigned short* x1b = (unsigned short*)(ws + 16 * MB);  // 16MB, dead after QKV
    float*          S   = (float*)(ws + 0);                 // 64MB, scores->probs
    float*          x1f = (float*)(ws + 64 * MB);           // 32MB, resid for lin2
    unsigned short* xn2 = (unsigned short*)(ws + 64 * MB);  // reuses x1f after LN2
    unsigned short* qb  = (unsigned short*)(ws + 96 * MB);  // 16MB
    unsigned short* kb  = (unsigned short*)(ws + 112 * MB); // 16MB
    unsigned short* vT  = (unsigned short*)(ws + 128 * MB); // 16MB transposed V
    unsigned short* attn= (unsigned short*)(ws + 96 * MB);  // reuses q after scores
    unsigned short* h   = (unsigned short*)(ws + 96 * MB);  // 32MB, reuses q/k
    float*          x2  = (float*)(ws + 144 * MB);          // 32MB
    unsigned short* wb1 = (unsigned short*)(ws + 176 * MB);
    unsigned short* wbq = (unsigned short*)(ws + 178 * MB);
    unsigned short* wbk = (unsigned short*)(ws + 180 * MB);
    unsigned short* wbv = (unsigned short*)(ws + 182 * MB);
    unsigned short* wb2 = (unsigned short*)(ws + 184 * MB);
    unsigned short* wbf1= (unsigned short*)(ws + 186 * MB); // 4MB
    unsigned short* wbf2= (unsigned short*)(ws + 190 * MB); // 4MB

    auto cvt = [&](const void* src, unsigned short* dst, long long n) {
        int n4 = (int)(n / 4);
        cvt_kernel<<<(n4 + 255) / 256, 256, 0, stream>>>((const float*)src, dst, n4);
    };
    cvt(d_in[3], wb1, 1048576);
    cvt(d_in[5], wbq, 1048576);
    cvt(d_in[7], wbk, 1048576);
    cvt(d_in[9], wbv, 1048576);
    cvt(d_in[11], wb2, 1048576);
    cvt(d_in[15], wbf1, 2097152);
    cvt(d_in[17], wbf2, 2097152);

    // LN1
    ln_kernel<<<8192, 256, 0, stream>>>(x, g1, be1, xn1);
    // lin1: fp32 (residual base) + bf16
    gemm_bt<4><<<dim3(16, 128, 1), 256, 0, stream>>>(xn1, 1024, 0, wb1, 1024, 0, b_lin1,
        nullptr, 0, x1f, x1b, 1024, 0, 1024, 1.f, 0);
    // Q (scale 1/32 folded in), K
    gemm_bt<2><<<dim3(16, 128, 1), 256, 0, stream>>>(x1b, 1024, 0, wbq, 1024, 0, bq,
        nullptr, 0, nullptr, qb, 1024, 0, 1024, 0.03125f, 0);
    gemm_bt<2><<<dim3(16, 128, 1), 256, 0, stream>>>(x1b, 1024, 0, wbk, 1024, 0, bk,
        nullptr, 0, nullptr, kb, 1024, 0, 1024, 1.f, 0);
    // V, transposed per batch: vT[b][d][t]
    gemm_bt<3><<<dim3(16, 32, 4), 256, 0, stream>>>(x1b, 1024, 2048LL * 1024, wbv, 1024, 0, bv,
        nullptr, 0, nullptr, vT, 2048, 2097152LL, 1024, 1.f, 0);
    // scores (causal blocks only), fp32
    gemm_bt<0><<<dim3(32, 32, 4), 256, 0, stream>>>(qb, 1024, 2097152LL, kb, 1024, 2097152LL,
        nullptr, nullptr, 0, S, nullptr, 2048, 4194304LL, 1024, 1.f, 1);
    // softmax -> bf16 probs in place
    softmax_kernel<<<dim3(2048, 4), 256, 0, stream>>>(S);
    // PV: attn = P @ V  (A = bf16 probs with row stride 4096, B = vT)
    gemm_bt<2><<<dim3(16, 32, 4), 256, 0, stream>>>((unsigned short*)S, 4096, 8388608LL,
        vT, 2048, 2097152LL, nullptr, nullptr, 0, nullptr, attn, 1024, 2097152LL, 2048, 1.f, 2);
    // lin2 + residual(x1f) -> x2 fp32
    gemm_bt<1><<<dim3(16, 128, 1), 256, 0, stream>>>(attn, 1024, 0, wb2, 1024, 0, b_lin2,
        x1f, 0, x2, nullptr, 1024, 0, 1024, 1.f, 0);
    // LN2
    ln_kernel<<<8192, 256, 0, stream>>>(x2, g2, be2, xn2);
    // FFN1 + exact GELU -> h bf16 [8192,2048]
    gemm_bt<5><<<dim3(32, 128, 1), 256, 0, stream>>>(xn2, 1024, 0, wbf1, 1024, 0, b_ff1,
        nullptr, 0, nullptr, h, 2048, 0, 1024, 1.f, 0);
    // FFN2 + residual(x2) -> d_out fp32
    gemm_bt<1><<<dim3(16, 128, 1), 256, 0, stream>>>(h, 2048, 0, wbf2, 2048, 0, b_ff2,
        x2, 0, (float*)d_out, nullptr, 1024, 0, 2048, 1.f, 0);
}

// Round 2
// 618.701 us; speedup vs baseline: 1.1218x; 1.1218x over previous
//
#include <hip/hip_runtime.h>

typedef __attribute__((ext_vector_type(4))) float f32x4;
typedef __attribute__((ext_vector_type(8))) short short8;
typedef __attribute__((ext_vector_type(4))) unsigned short u16x4;
typedef __attribute__((ext_vector_type(8))) unsigned short u16x8;

#define MFMA(a, b, c) __builtin_amdgcn_mfma_f32_16x16x32_bf16(a, b, c, 0, 0, 0)
// async global->LDS, 16B per lane; LDS dest is wave-uniform base + lane*16
#define GLOAD16(g, l) __builtin_amdgcn_global_load_lds( \
    (const __attribute__((address_space(1))) unsigned int*)(g), \
    (__attribute__((address_space(3))) unsigned int*)(l), 16, 0, 0)

__device__ inline unsigned short f2bf(float f) {
    unsigned int u = __float_as_uint(f);
    u += 0x7fffu + ((u >> 16) & 1u);   // RNE
    return (unsigned short)(u >> 16);
}

// ---------------------------------------------------------------------------
// fp32 -> bf16 elementwise (weights)
__global__ __launch_bounds__(256) void cvt_kernel(const float* __restrict__ in,
                                                  unsigned short* __restrict__ out, int n4) {
    int i = blockIdx.x * 256 + threadIdx.x;
    if (i < n4) {
        f32x4 v = *(const f32x4*)(in + (long long)i * 4);
        u16x4 o;
#pragma unroll
        for (int j = 0; j < 4; j++) o[j] = f2bf(v[j]);
        *(u16x4*)&out[(long long)i * 4] = o;
    }
}

// ---------------------------------------------------------------------------
// LayerNorm: fp32 [rows,1024] -> bf16 out. One block per row.
__global__ __launch_bounds__(256) void ln_kernel(const float* __restrict__ x,
                                                 const float* __restrict__ g,
                                                 const float* __restrict__ be,
                                                 unsigned short* __restrict__ out) {
    const int row = blockIdx.x, tid = threadIdx.x;
    const float* px = x + (long long)row * 1024;
    f32x4 v = *(const f32x4*)(px + tid * 4);
    float s = v[0] + v[1] + v[2] + v[3];
    float q = v[0] * v[0] + v[1] * v[1] + v[2] * v[2] + v[3] * v[3];
#pragma unroll
    for (int o = 32; o; o >>= 1) { s += __shfl_xor(s, o); q += __shfl_xor(q, o); }
    __shared__ float sm[10];
    const int lane = tid & 63, wid = tid >> 6;
    if (lane == 0) { sm[wid] = s; sm[4 + wid] = q; }
    __syncthreads();
    if (tid == 0) {
        float ts = sm[0] + sm[1] + sm[2] + sm[3];
        float tq = sm[4] + sm[5] + sm[6] + sm[7];
        float mean = ts * (1.f / 1024.f);
        float var = tq * (1.f / 1024.f) - mean * mean;
        sm[8] = mean; sm[9] = rsqrtf(var + 1e-5f);
    }
    __syncthreads();
    float mean = sm[8], rs = sm[9];
    f32x4 gg = *(const f32x4*)(g + tid * 4);
    f32x4 bb = *(const f32x4*)(be + tid * 4);
    u16x4 o;
#pragma unroll
    for (int i = 0; i < 4; i++) o[i] = f2bf((v[i] - mean) * rs * gg[i] + bb[i]);
    *(u16x4*)&out[(long long)row * 1024 + tid * 4] = o;
}

// ---------------------------------------------------------------------------
// Causal softmax over row [0..t], writes bf16 probs IN-PLACE over the fp32 row
// (first half of each 8KB row). Zeros for s>t. grid (T, B).
__global__ __launch_bounds__(256) void softmax_kernel(float* __restrict__ S) {
    const int T = 2048;
    const int t = blockIdx.x, b = blockIdx.y, tid = threadIdx.x;
    float* row = S + ((long long)b * T + t) * T;
    const int base = tid * 8;
    f32x4 v0 = *(const f32x4*)(row + base);
    f32x4 v1 = *(const f32x4*)(row + base + 4);
    float mx = -1e30f;
#pragma unroll
    for (int i = 0; i < 4; i++) {
        if (base + i <= t)     mx = fmaxf(mx, v0[i]);
        if (base + 4 + i <= t) mx = fmaxf(mx, v1[i]);
    }
#pragma unroll
    for (int o = 32; o; o >>= 1) mx = fmaxf(mx, __shfl_xor(mx, o));
    __shared__ float sm[10];
    const int lane = tid & 63, wid = tid >> 6;
    if (lane == 0) sm[wid] = mx;
    __syncthreads();
    if (tid == 0) sm[8] = fmaxf(fmaxf(sm[0], sm[1]), fmaxf(sm[2], sm[3]));
    __syncthreads();
    float M = sm[8];
    float e[8]; float s = 0.f;
#pragma unroll
    for (int i = 0; i < 4; i++) {
        e[i]     = (base + i <= t)     ? __expf(v0[i] - M) : 0.f;
        e[4 + i] = (base + 4 + i <= t) ? __expf(v1[i] - M) : 0.f;
        s += e[i] + e[4 + i];
    }
#pragma unroll
    for (int o = 32; o; o >>= 1) s += __shfl_xor(s, o);
    if (lane == 0) sm[4 + wid] = s;
    __syncthreads();
    if (tid == 0) sm[9] = 1.f / (sm[4] + sm[5] + sm[6] + sm[7]);
    __syncthreads();
    float inv = sm[9];
    unsigned short* P = (unsigned short*)row;
    u16x8 o;
#pragma unroll
    for (int i = 0; i < 8; i++) o[i] = f2bf(e[i] * inv);
    *(u16x8*)&P[base] = o;   // safe: all loads done before barriers above
}

// ---------------------------------------------------------------------------
// GEMM (m97 structure): Y[M,N] = A[M,K](bf16) @ B[N,K]^T(bf16) (+bias).
// 128x128 tile, 4 waves (2x2), each wave 64x64 = 4x4 of 16x16x32 MFMA frags.
// Staging: global_load_lds width=16 into LINEAR LDS [128][32] bf16
// (wave-uniform dest + lane*16; per-lane global source). 2 barriers/K-step.
// MODE: 0 fp32 out | 1 fp32 out + residual | 2 bf16 out (*scale after bias)
//       3 bf16 out TRANSPOSED (out[n*ldo+m]) | 4 fp32 AND bf16 | 5 bf16 GELU
// flags: bit0 = causal block skip (n0>m0), bit1 = K limited to m0+128
template <int MODE>
__global__ __launch_bounds__(256) void gemm_bt(
    const unsigned short* __restrict__ A, int lda, long long sA,
    const unsigned short* __restrict__ Bw, int ldb, long long sB,
    const float* __restrict__ bias,
    const float* __restrict__ resid, long long sR,
    float* __restrict__ outf, unsigned short* __restrict__ outb,
    int ldo, long long sO, int K, float scale, int flags) {
    const int m0 = blockIdx.y * 128, n0 = blockIdx.x * 128;
    if ((flags & 1) && n0 > m0) return;
    const int bz = blockIdx.z;
    A += (long long)bz * sA; Bw += (long long)bz * sB;
    if (resid) resid += (long long)bz * sR;
    if (outf) outf += (long long)bz * sO;
    if (outb) outb += (long long)bz * sO;
    const int Keff = (flags & 2) ? (m0 + 128 < K ? m0 + 128 : K) : K;

    __shared__ __align__(16) unsigned short As[128 * 32];
    __shared__ __align__(16) unsigned short Bs[128 * 32];

    const int tid = threadIdx.x, lane = tid & 63, wid = tid >> 6;
    // staging: wave w owns rows [32w, 32w+32); lane l -> row 32w + l/4, col (l%4)*8
    const int srow = (wid << 5) + (lane >> 2);
    const int scol = (lane & 3) * 8;
    const unsigned short* gA = A + (long long)(m0 + srow) * lda + scol;
    const unsigned short* gB = Bw + (long long)(n0 + srow) * ldb + scol;
    unsigned short* lA = &As[wid * 1024];   // wave-uniform LDS dest (bytes: wid*2048)
    unsigned short* lB = &Bs[wid * 1024];
    const long long a16 = 16LL * lda, b16 = 16LL * ldb;

    const int wm = (wid >> 1) * 64, wn = (wid & 1) * 64;
    const int fr = lane & 15, fk = (lane >> 4) * 8;

    f32x4 acc[4][4] = {};
    for (int k0 = 0; k0 < Keff; k0 += 32) {
        GLOAD16(gA + k0, lA);
        GLOAD16(gA + k0 + a16, lA + 512);
        GLOAD16(gB + k0, lB);
        GLOAD16(gB + k0 + b16, lB + 512);
        __syncthreads();   // drains vmcnt -> LDS tile complete
        short8 a[4], b[4];
#pragma unroll
        for (int i = 0; i < 4; i++) {
            a[i] = *(const short8*)&As[(wm + i * 16 + fr) * 32 + fk];
            b[i] = *(const short8*)&Bs[(wn + i * 16 + fr) * 32 + fk];
        }
#pragma unroll
        for (int i = 0; i < 4; i++)
#pragma unroll
            for (int j = 0; j < 4; j++)
                acc[i][j] = MFMA(a[i], b[j], acc[i][j]);
        __syncthreads();
    }

    const int cc = lane & 15, rr = (lane >> 4) * 4;
#pragma unroll
    for (int fm = 0; fm < 4; fm++)
#pragma unroll
        for (int fn = 0; fn < 4; fn++) {
            f32x4 av = acc[fm][fn];
            int colg = n0 + wn + fn * 16 + cc;
            int rowg0 = m0 + wm + fm * 16 + rr;
            float bv = bias ? bias[colg] : 0.f;
            if (MODE == 3) {
                u16x4 o;
#pragma unroll
                for (int i = 0; i < 4; i++) o[i] = f2bf((av[i] + bv) * scale);
                *(u16x4*)&outb[(long long)colg * ldo + rowg0] = o;
            } else {
#pragma unroll
                for (int i = 0; i < 4; i++) {
                    float v = av[i] + bv;
                    long long idx = (long long)(rowg0 + i) * ldo + colg;
                    if (MODE == 0) outf[idx] = v;
                    if (MODE == 1) outf[idx] = v + resid[idx];
                    if (MODE == 2) outb[idx] = f2bf(v * scale);
                    if (MODE == 4) { outf[idx] = v; outb[idx] = f2bf(v); }
                    if (MODE == 5) outb[idx] = f2bf(0.5f * v * (1.f + erff(v * 0.70710678f)));
                }
            }
        }
}

// ---------------------------------------------------------------------------
extern "C" void kernel_launch(void* const* d_in, const int* in_sizes, int n_in,
                              void* d_out, int out_size, void* d_ws, size_t ws_size,
                              hipStream_t stream) {
    const float* x      = (const float*)d_in[0];
    const float* g1     = (const float*)d_in[1];
    const float* be1    = (const float*)d_in[2];
    const float* b_lin1 = (const float*)d_in[4];
    const float* bq     = (const float*)d_in[6];
    const float* bk     = (const float*)d_in[8];
    const float* bv     = (const float*)d_in[10];
    const float* b_lin2 = (const float*)d_in[12];
    const float* g2     = (const float*)d_in[13];
    const float* be2    = (const float*)d_in[14];
    const float* b_ff1  = (const float*)d_in[16];
    const float* b_ff2  = (const float*)d_in[18];

    const long long MB = 1024LL * 1024LL;
    char* ws = (char*)d_ws;
    // lifetime-overlapped layout (194MB total)
    unsigned short* xn1 = (unsigned short*)(ws + 0);        // 16MB, dead after lin1
    unsigned short* x1b = (unsigned short*)(ws + 16 * MB);  // 16MB, dead after QKV
    float*          S   = (float*)(ws + 0);                 // 64MB, scores->probs
    float*          x1f = (float*)(ws + 64 * MB);           // 32MB, resid for lin2
    unsigned short* xn2 = (unsigned short*)(ws + 64 * MB);  // reuses x1f after LN2
    unsigned short* qb  = (unsigned short*)(ws + 96 * MB);  // 16MB
    unsigned short* kb  = (unsigned short*)(ws + 112 * MB); // 16MB
    unsigned short* vT  = (unsigned short*)(ws + 128 * MB); // 16MB transposed V
    unsigned short* attn= (unsigned short*)(ws + 96 * MB);  // reuses q after scores
    unsigned short* h   = (unsigned short*)(ws + 96 * MB);  // 32MB, reuses q/k
    float*          x2  = (float*)(ws + 144 * MB);          // 32MB
    unsigned short* wb1 = (unsigned short*)(ws + 176 * MB);
    unsigned short* wbq = (unsigned short*)(ws + 178 * MB);
    unsigned short* wbk = (unsigned short*)(ws + 180 * MB);
    unsigned short* wbv = (unsigned short*)(ws + 182 * MB);
    unsigned short* wb2 = (unsigned short*)(ws + 184 * MB);
    unsigned short* wbf1= (unsigned short*)(ws + 186 * MB); // 4MB
    unsigned short* wbf2= (unsigned short*)(ws + 190 * MB); // 4MB

    auto cvt = [&](const void* src, unsigned short* dst, long long n) {
        int n4 = (int)(n / 4);
        cvt_kernel<<<(n4 + 255) / 256, 256, 0, stream>>>((const float*)src, dst, n4);
    };
    cvt(d_in[3], wb1, 1048576);
    cvt(d_in[5], wbq, 1048576);
    cvt(d_in[7], wbk, 1048576);
    cvt(d_in[9], wbv, 1048576);
    cvt(d_in[11], wb2, 1048576);
    cvt(d_in[15], wbf1, 2097152);
    cvt(d_in[17], wbf2, 2097152);

    // LN1
    ln_kernel<<<8192, 256, 0, stream>>>(x, g1, be1, xn1);
    // lin1: fp32 (residual base) + bf16
    gemm_bt<4><<<dim3(8, 64, 1), 256, 0, stream>>>(xn1, 1024, 0, wb1, 1024, 0, b_lin1,
        nullptr, 0, x1f, x1b, 1024, 0, 1024, 1.f, 0);
    // Q (scale 1/32 folded in), K
    gemm_bt<2><<<dim3(8, 64, 1), 256, 0, stream>>>(x1b, 1024, 0, wbq, 1024, 0, bq,
        nullptr, 0, nullptr, qb, 1024, 0, 1024, 0.03125f, 0);
    gemm_bt<2><<<dim3(8, 64, 1), 256, 0, stream>>>(x1b, 1024, 0, wbk, 1024, 0, bk,
        nullptr, 0, nullptr, kb, 1024, 0, 1024, 1.f, 0);
    // V, transposed per batch: vT[b][d][t]
    gemm_bt<3><<<dim3(8, 16, 4), 256, 0, stream>>>(x1b, 1024, 2048LL * 1024, wbv, 1024, 0, bv,
        nullptr, 0, nullptr, vT, 2048, 2097152LL, 1024, 1.f, 0);
    // scores (causal blocks only), fp32
    gemm_bt<0><<<dim3(16, 16, 4), 256, 0, stream>>>(qb, 1024, 2097152LL, kb, 1024, 2097152LL,
        nullptr, nullptr, 0, S, nullptr, 2048, 4194304LL, 1024, 1.f, 1);
    // softmax -> bf16 probs in place
    softmax_kernel<<<dim3(2048, 4), 256, 0, stream>>>(S);
    // PV: attn = P @ V  (A = bf16 probs with row stride 4096, B = vT), K-limit
    gemm_bt<2><<<dim3(8, 16, 4), 256, 0, stream>>>((unsigned short*)S, 4096, 8388608LL,
        vT, 2048, 2097152LL, nullptr, nullptr, 0, nullptr, attn, 1024, 2097152LL, 2048, 1.f, 2);
    // lin2 + residual(x1f) -> x2 fp32
    gemm_bt<1><<<dim3(8, 64, 1), 256, 0, stream>>>(attn, 1024, 0, wb2, 1024, 0, b_lin2,
        x1f, 0, x2, nullptr, 1024, 0, 1024, 1.f, 0);
    // LN2
    ln_kernel<<<8192, 256, 0, stream>>>(x2, g2, be2, xn2);
    // FFN1 + exact GELU -> h bf16 [8192,2048]
    gemm_bt<5><<<dim3(16, 64, 1), 256, 0, stream>>>(xn2, 1024, 0, wbf1, 1024, 0, b_ff1,
        nullptr, 0, nullptr, h, 2048, 0, 1024, 1.f, 0);
    // FFN2 + residual(x2) -> d_out fp32
    gemm_bt<1><<<dim3(8, 64, 1), 256, 0, stream>>>(h, 2048, 0, wbf2, 2048, 0, b_ff2,
        x2, 0, (float*)d_out, nullptr, 1024, 0, 2048, 1.f, 0);
}

// Round 3
// 512.750 us; speedup vs baseline: 1.3536x; 1.2066x over previous
//
#include <hip/hip_runtime.h>

typedef __attribute__((ext_vector_type(4))) float f32x4;
typedef __attribute__((ext_vector_type(8))) short short8;
typedef __attribute__((ext_vector_type(4))) unsigned short u16x4;
typedef __attribute__((ext_vector_type(8))) unsigned short u16x8;

#define MFMA(a, b, c) __builtin_amdgcn_mfma_f32_16x16x32_bf16(a, b, c, 0, 0, 0)
// async global->LDS, 16B per lane; LDS dest is wave-uniform base + lane*16
#define GLOAD16(g, l) __builtin_amdgcn_global_load_lds( \
    (const __attribute__((address_space(1))) unsigned int*)(g), \
    (__attribute__((address_space(3))) unsigned int*)(l), 16, 0, 0)

#define BARX() __builtin_amdgcn_s_barrier()
#define LGK0() asm volatile("s_waitcnt lgkmcnt(0)" ::: "memory")
#define VM6 asm volatile("s_waitcnt vmcnt(6)" ::: "memory")
#define VM0 asm volatile("s_waitcnt vmcnt(0)" ::: "memory")
#define NOWAIT ((void)0)

__device__ inline unsigned short f2bf(float f) {
    unsigned int u = __float_as_uint(f);
    u += 0x7fffu + ((u >> 16) & 1u);   // RNE
    return (unsigned short)(u >> 16);
}

// ---------------------------------------------------------------------------
__global__ __launch_bounds__(256) void cvt_kernel(const float* __restrict__ in,
                                                  unsigned short* __restrict__ out, int n4) {
    int i = blockIdx.x * 256 + threadIdx.x;
    if (i < n4) {
        f32x4 v = *(const f32x4*)(in + (long long)i * 4);
        u16x4 o;
#pragma unroll
        for (int j = 0; j < 4; j++) o[j] = f2bf(v[j]);
        *(u16x4*)&out[(long long)i * 4] = o;
    }
}

// ---------------------------------------------------------------------------
__global__ __launch_bounds__(256) void ln_kernel(const float* __restrict__ x,
                                                 const float* __restrict__ g,
                                                 const float* __restrict__ be,
                                                 unsigned short* __restrict__ out) {
    const int row = blockIdx.x, tid = threadIdx.x;
    const float* px = x + (long long)row * 1024;
    f32x4 v = *(const f32x4*)(px + tid * 4);
    float s = v[0] + v[1] + v[2] + v[3];
    float q = v[0] * v[0] + v[1] * v[1] + v[2] * v[2] + v[3] * v[3];
#pragma unroll
    for (int o = 32; o; o >>= 1) { s += __shfl_xor(s, o); q += __shfl_xor(q, o); }
    __shared__ float sm[10];
    const int lane = tid & 63, wid = tid >> 6;
    if (lane == 0) { sm[wid] = s; sm[4 + wid] = q; }
    __syncthreads();
    if (tid == 0) {
        float ts = sm[0] + sm[1] + sm[2] + sm[3];
        float tq = sm[4] + sm[5] + sm[6] + sm[7];
        float mean = ts * (1.f / 1024.f);
        float var = tq * (1.f / 1024.f) - mean * mean;
        sm[8] = mean; sm[9] = rsqrtf(var + 1e-5f);
    }
    __syncthreads();
    float mean = sm[8], rs = sm[9];
    f32x4 gg = *(const f32x4*)(g + tid * 4);
    f32x4 bb = *(const f32x4*)(be + tid * 4);
    u16x4 o;
#pragma unroll
    for (int i = 0; i < 4; i++) o[i] = f2bf((v[i] - mean) * rs * gg[i] + bb[i]);
    *(u16x4*)&out[(long long)row * 1024 + tid * 4] = o;
}

// ---------------------------------------------------------------------------
// Causal softmax over row [0..t], writes bf16 probs IN-PLACE over the fp32 row.
__global__ __launch_bounds__(256) void softmax_kernel(float* __restrict__ S) {
    const int T = 2048;
    const int t = blockIdx.x, b = blockIdx.y, tid = threadIdx.x;
    float* row = S + ((long long)b * T + t) * T;
    const int base = tid * 8;
    f32x4 v0 = *(const f32x4*)(row + base);
    f32x4 v1 = *(const f32x4*)(row + base + 4);
    float mx = -1e30f;
#pragma unroll
    for (int i = 0; i < 4; i++) {
        if (base + i <= t)     mx = fmaxf(mx, v0[i]);
        if (base + 4 + i <= t) mx = fmaxf(mx, v1[i]);
    }
#pragma unroll
    for (int o = 32; o; o >>= 1) mx = fmaxf(mx, __shfl_xor(mx, o));
    __shared__ float sm[10];
    const int lane = tid & 63, wid = tid >> 6;
    if (lane == 0) sm[wid] = mx;
    __syncthreads();
    if (tid == 0) sm[8] = fmaxf(fmaxf(sm[0], sm[1]), fmaxf(sm[2], sm[3]));
    __syncthreads();
    float M = sm[8];
    float e[8]; float s = 0.f;
#pragma unroll
    for (int i = 0; i < 4; i++) {
        e[i]     = (base + i <= t)     ? __expf(v0[i] - M) : 0.f;
        e[4 + i] = (base + 4 + i <= t) ? __expf(v1[i] - M) : 0.f;
        s += e[i] + e[4 + i];
    }
#pragma unroll
    for (int o = 32; o; o >>= 1) s += __shfl_xor(s, o);
    if (lane == 0) sm[4 + wid] = s;
    __syncthreads();
    if (tid == 0) sm[9] = 1.f / (sm[4] + sm[5] + sm[6] + sm[7]);
    __syncthreads();
    float inv = sm[9];
    unsigned short* P = (unsigned short*)row;
    u16x8 o;
#pragma unroll
    for (int i = 0; i < 8; i++) o[i] = f2bf(e[i] * inv);
    *(u16x8*)&P[base] = o;
}

// ---------------------------------------------------------------------------
// GEMM, 8-phase-style schedule: Y[M,N] = A[M,K](bf16) @ B[N,K]^T(bf16) (+bias)
// Tile 256x128, BK=64, 512 threads (8 waves 4Mx2N, 64x64/wave = 4x4 frags).
// Triple-buffered LDS (3 x 48KB), prefetch depth 2, counted vmcnt(6) at tile
// end (never drain-0 in steady state). T2 XOR swizzle: 16B chunk ^= (row&7),
// applied on the READ side and pre-applied to the global SOURCE (linear
// global_load_lds dest). 4 phases/K-tile: {ds_read frags | issue gloads |
// barrier | lgkmcnt(0) | setprio(1) 8xMFMA setprio(0) | barrier}.
// MODE: 0 fp32 | 1 fp32+residual | 2 bf16 (*scale) | 3 bf16 transposed
//       4 fp32 AND bf16 | 5 bf16 GELU
// flags: bit0 = causal block skip, bit1 = K limited to m0+256
#define TILE(CB, PB, KPRE, PF, WAITER) do {                                         \
    const unsigned short* Lc = LDS + (CB) * 24576;                                  \
    unsigned short* Lp = LDS + (PB) * 24576;                                        \
    short8 Af0, Af1, Af2, Af3, Bf[4];                                               \
    Af0 = *(const short8*)(Lc + ao[0] + ks0);                                       \
    Af1 = *(const short8*)(Lc + ao[1] + ks0);                                       \
    _Pragma("unroll") for (int j = 0; j < 4; j++)                                   \
        Bf[j] = *(const short8*)(Lc + bo[j] + ks0);                                 \
    if (PF) { GLOAD16(srcA[0] + (KPRE), Lp + dstA[0]);                              \
              GLOAD16(srcA[1] + (KPRE), Lp + dstA[1]);                              \
              GLOAD16(srcA[2] + (KPRE), Lp + dstA[2]); }                            \
    BARX(); LGK0();                                                                 \
    __builtin_amdgcn_s_setprio(1);                                                  \
    _Pragma("unroll") for (int j = 0; j < 4; j++) {                                 \
        acc[0][j] = MFMA(Af0, Bf[j], acc[0][j]);                                    \
        acc[1][j] = MFMA(Af1, Bf[j], acc[1][j]); }                                  \
    __builtin_amdgcn_s_setprio(0); BARX();                                          \
    Af2 = *(const short8*)(Lc + ao[2] + ks0);                                       \
    Af3 = *(const short8*)(Lc + ao[3] + ks0);                                       \
    if (PF) { GLOAD16(srcA[3] + (KPRE), Lp + dstA[3]);                              \
              GLOAD16(srcB[0] + (KPRE), Lp + dstB[0]);                              \
              GLOAD16(srcB[1] + (KPRE), Lp + dstB[1]); }                            \
    BARX(); LGK0();                                                                 \
    __builtin_amdgcn_s_setprio(1);                                                  \
    _Pragma("unroll") for (int j = 0; j < 4; j++) {                                 \
        acc[2][j] = MFMA(Af2, Bf[j], acc[2][j]);                                    \
        acc[3][j] = MFMA(Af3, Bf[j], acc[3][j]); }                                  \
    __builtin_amdgcn_s_setprio(0); BARX();                                          \
    Af0 = *(const short8*)(Lc + ao[0] + ks1);                                       \
    Af1 = *(const short8*)(Lc + ao[1] + ks1);                                       \
    _Pragma("unroll") for (int j = 0; j < 4; j++)                                   \
        Bf[j] = *(const short8*)(Lc + bo[j] + ks1);                                 \
    BARX(); LGK0();                                                                 \
    __builtin_amdgcn_s_setprio(1);                                                  \
    _Pragma("unroll") for (int j = 0; j < 4; j++) {                                 \
        acc[0][j] = MFMA(Af0, Bf[j], acc[0][j]);                                    \
        acc[1][j] = MFMA(Af1, Bf[j], acc[1][j]); }                                  \
    __builtin_amdgcn_s_setprio(0); BARX();                                          \
    Af2 = *(const short8*)(Lc + ao[2] + ks1);                                       \
    Af3 = *(const short8*)(Lc + ao[3] + ks1);                                       \
    WAITER;                                                                         \
    BARX(); LGK0();                                                                 \
    __builtin_amdgcn_s_setprio(1);                                                  \
    _Pragma("unroll") for (int j = 0; j < 4; j++) {                                 \
        acc[2][j] = MFMA(Af2, Bf[j], acc[2][j]);                                    \
        acc[3][j] = MFMA(Af3, Bf[j], acc[3][j]); }                                  \
    __builtin_amdgcn_s_setprio(0); BARX();                                          \
} while (0)

template <int MODE>
__global__ __launch_bounds__(512, 2) void gemm_bt(
    const unsigned short* __restrict__ A, int lda, long long sA,
    const unsigned short* __restrict__ Bw, int ldb, long long sB,
    const float* __restrict__ bias,
    const float* __restrict__ resid, long long sR,
    float* __restrict__ outf, unsigned short* __restrict__ outb,
    int ldo, long long sO, int K, float scale, int flags) {
    const int m0 = blockIdx.y * 256, n0 = blockIdx.x * 128;
    if ((flags & 1) && n0 >= m0 + 256) return;
    const int bz = blockIdx.z;
    A += (long long)bz * sA; Bw += (long long)bz * sB;
    if (resid) resid += (long long)bz * sR;
    if (outf) outf += (long long)bz * sO;
    if (outb) outb += (long long)bz * sO;
    const int Keff = (flags & 2) ? (m0 + 256 < K ? m0 + 256 : K) : K;
    const int nt = Keff >> 6;   // >= 4 for all shapes here

    __shared__ __align__(16) unsigned short LDS[3 * 24576];   // 144 KB

    const int tid = threadIdx.x, lane = tid & 63, wid = tid >> 6;

    // --- staging maps (pre-swizzled global source, linear LDS dest) ---
    const unsigned short* srcA[4]; int dstA[4];
    const unsigned short* srcB[2]; int dstB[2];
#pragma unroll
    for (int g = 0; g < 4; g++) {
        int p = g * 512 + wid * 64 + lane;       // 16B-chunk index in A tile
        int r = p >> 3, cs = (p & 7) ^ (r & 7);  // inverse swizzle on source
        srcA[g] = A + (long long)(m0 + r) * lda + cs * 8;
        dstA[g] = g * 4096 + wid * 512;          // wave-uniform (shorts)
    }
#pragma unroll
    for (int g = 0; g < 2; g++) {
        int p = g * 512 + wid * 64 + lane;
        int r = p >> 3, cs = (p & 7) ^ (r & 7);
        srcB[g] = Bw + (long long)(n0 + r) * ldb + cs * 8;
        dstB[g] = 16384 + g * 4096 + wid * 512;
    }

    // --- fragment read offsets (swizzled) ---
    const int wm = (wid >> 1) * 64, wn = (wid & 1) * 64;
    const int fr = lane & 15;
    int ao[4], bo[4];
#pragma unroll
    for (int i = 0; i < 4; i++) ao[i] = (wm + i * 16 + fr) * 64;
#pragma unroll
    for (int j = 0; j < 4; j++) bo[j] = 16384 + (wn + j * 16 + fr) * 64;
    const int ks0 = (((lane >> 4)) ^ (fr & 7)) * 8;
    const int ks1 = ((4 + (lane >> 4)) ^ (fr & 7)) * 8;

    f32x4 acc[4][4] = {};

    // --- prologue: issue tiles 0 and 1 ---
#pragma unroll
    for (int g = 0; g < 4; g++) GLOAD16(srcA[g], LDS + dstA[g]);
#pragma unroll
    for (int g = 0; g < 2; g++) GLOAD16(srcB[g], LDS + dstB[g]);
#pragma unroll
    for (int g = 0; g < 4; g++) GLOAD16(srcA[g] + 64, LDS + 24576 + dstA[g]);
#pragma unroll
    for (int g = 0; g < 2; g++) GLOAD16(srcB[g] + 64, LDS + 24576 + dstB[g]);
    VM6; BARX();
    __builtin_amdgcn_sched_barrier(0);

    int c = 0, p = 2, kpre = 128;
    for (int t = 0; t < nt - 2; ++t) {
        TILE(c, p, kpre, true, VM6);
        c = (c == 2) ? 0 : c + 1;
        p = (p == 2) ? 0 : p + 1;
        kpre += 64;
    }
    TILE(c, p, 0, false, VM0);
    c = (c == 2) ? 0 : c + 1;
    TILE(c, p, 0, false, NOWAIT);

    // --- epilogue ---
    const int cc = lane & 15, rr = (lane >> 4) * 4;
#pragma unroll
    for (int fm = 0; fm < 4; fm++)
#pragma unroll
        for (int fn = 0; fn < 4; fn++) {
            f32x4 av = acc[fm][fn];
            int colg = n0 + wn + fn * 16 + cc;
            int rowg0 = m0 + wm + fm * 16 + rr;
            float bv = bias ? bias[colg] : 0.f;
            if (MODE == 3) {
                u16x4 o;
#pragma unroll
                for (int i = 0; i < 4; i++) o[i] = f2bf((av[i] + bv) * scale);
                *(u16x4*)&outb[(long long)colg * ldo + rowg0] = o;
            } else {
#pragma unroll
                for (int i = 0; i < 4; i++) {
                    float v = av[i] + bv;
                    long long idx = (long long)(rowg0 + i) * ldo + colg;
                    if (MODE == 0) outf[idx] = v;
                    if (MODE == 1) outf[idx] = v + resid[idx];
                    if (MODE == 2) outb[idx] = f2bf(v * scale);
                    if (MODE == 4) { outf[idx] = v; outb[idx] = f2bf(v); }
                    if (MODE == 5) outb[idx] = f2bf(0.5f * v * (1.f + erff(v * 0.70710678f)));
                }
            }
        }
}

// ---------------------------------------------------------------------------
extern "C" void kernel_launch(void* const* d_in, const int* in_sizes, int n_in,
                              void* d_out, int out_size, void* d_ws, size_t ws_size,
                              hipStream_t stream) {
    const float* x      = (const float*)d_in[0];
    const float* g1     = (const float*)d_in[1];
    const float* be1    = (const float*)d_in[2];
    const float* b_lin1 = (const float*)d_in[4];
    const float* bq     = (const float*)d_in[6];
    const float* bk     = (const float*)d_in[8];
    const float* bv     = (const float*)d_in[10];
    const float* b_lin2 = (const float*)d_in[12];
    const float* g2     = (const float*)d_in[13];
    const float* be2    = (const float*)d_in[14];
    const float* b_ff1  = (const float*)d_in[16];
    const float* b_ff2  = (const float*)d_in[18];

    const long long MB = 1024LL * 1024LL;
    char* ws = (char*)d_ws;
    unsigned short* xn1 = (unsigned short*)(ws + 0);        // 16MB, dead after lin1
    unsigned short* x1b = (unsigned short*)(ws + 16 * MB);  // 16MB, dead after QKV
    float*          S   = (float*)(ws + 0);                 // 64MB, scores->probs
    float*          x1f = (float*)(ws + 64 * MB);           // 32MB, resid for lin2
    unsigned short* xn2 = (unsigned short*)(ws + 64 * MB);  // reuses x1f after LN2
    unsigned short* qb  = (unsigned short*)(ws + 96 * MB);  // 16MB
    unsigned short* kb  = (unsigned short*)(ws + 112 * MB); // 16MB
    unsigned short* vT  = (unsigned short*)(ws + 128 * MB); // 16MB transposed V
    unsigned short* attn= (unsigned short*)(ws + 96 * MB);  // reuses q after scores
    unsigned short* h   = (unsigned short*)(ws + 96 * MB);  // 32MB, reuses q/k
    float*          x2  = (float*)(ws + 144 * MB);          // 32MB
    unsigned short* wb1 = (unsigned short*)(ws + 176 * MB);
    unsigned short* wbq = (unsigned short*)(ws + 178 * MB);
    unsigned short* wbk = (unsigned short*)(ws + 180 * MB);
    unsigned short* wbv = (unsigned short*)(ws + 182 * MB);
    unsigned short* wb2 = (unsigned short*)(ws + 184 * MB);
    unsigned short* wbf1= (unsigned short*)(ws + 186 * MB); // 4MB
    unsigned short* wbf2= (unsigned short*)(ws + 190 * MB); // 4MB

    auto cvt = [&](const void* src, unsigned short* dst, long long n) {
        int n4 = (int)(n / 4);
        cvt_kernel<<<(n4 + 255) / 256, 256, 0, stream>>>((const float*)src, dst, n4);
    };
    cvt(d_in[3], wb1, 1048576);
    cvt(d_in[5], wbq, 1048576);
    cvt(d_in[7], wbk, 1048576);
    cvt(d_in[9], wbv, 1048576);
    cvt(d_in[11], wb2, 1048576);
    cvt(d_in[15], wbf1, 2097152);
    cvt(d_in[17], wbf2, 2097152);

    // LN1
    ln_kernel<<<8192, 256, 0, stream>>>(x, g1, be1, xn1);
    // lin1: fp32 (residual base) + bf16
    gemm_bt<4><<<dim3(8, 32, 1), 512, 0, stream>>>(xn1, 1024, 0, wb1, 1024, 0, b_lin1,
        nullptr, 0, x1f, x1b, 1024, 0, 1024, 1.f, 0);
    // Q (scale 1/32 folded in), K
    gemm_bt<2><<<dim3(8, 32, 1), 512, 0, stream>>>(x1b, 1024, 0, wbq, 1024, 0, bq,
        nullptr, 0, nullptr, qb, 1024, 0, 1024, 0.03125f, 0);
    gemm_bt<2><<<dim3(8, 32, 1), 512, 0, stream>>>(x1b, 1024, 0, wbk, 1024, 0, bk,
        nullptr, 0, nullptr, kb, 1024, 0, 1024, 1.f, 0);
    // V, transposed per batch: vT[b][d][t]
    gemm_bt<3><<<dim3(8, 8, 4), 512, 0, stream>>>(x1b, 1024, 2048LL * 1024, wbv, 1024, 0, bv,
        nullptr, 0, nullptr, vT, 2048, 2097152LL, 1024, 1.f, 0);
    // scores (causal blocks only), fp32
    gemm_bt<0><<<dim3(16, 8, 4), 512, 0, stream>>>(qb, 1024, 2097152LL, kb, 1024, 2097152LL,
        nullptr, nullptr, 0, S, nullptr, 2048, 4194304LL, 1024, 1.f, 1);
    // softmax -> bf16 probs in place
    softmax_kernel<<<dim3(2048, 4), 256, 0, stream>>>(S);
    // PV: attn = P @ V  (A = bf16 probs with row stride 4096, B = vT), K-limit
    gemm_bt<2><<<dim3(8, 8, 4), 512, 0, stream>>>((unsigned short*)S, 4096, 8388608LL,
        vT, 2048, 2097152LL, nullptr, nullptr, 0, nullptr, attn, 1024, 2097152LL, 2048, 1.f, 2);
    // lin2 + residual(x1f) -> x2 fp32
    gemm_bt<1><<<dim3(8, 32, 1), 512, 0, stream>>>(attn, 1024, 0, wb2, 1024, 0, b_lin2,
        x1f, 0, x2, nullptr, 1024, 0, 1024, 1.f, 0);
    // LN2
    ln_kernel<<<8192, 256, 0, stream>>>(x2, g2, be2, xn2);
    // FFN1 + exact GELU -> h bf16 [8192,2048]
    gemm_bt<5><<<dim3(16, 32, 1), 512, 0, stream>>>(xn2, 1024, 0, wbf1, 1024, 0, b_ff1,
        nullptr, 0, nullptr, h, 2048, 0, 1024, 1.f, 0);
    // FFN2 + residual(x2) -> d_out fp32
    gemm_bt<1><<<dim3(8, 32, 1), 512, 0, stream>>>(h, 2048, 0, wbf2, 2048, 0, b_ff2,
        x2, 0, (float*)d_out, nullptr, 1024, 0, 2048, 1.f, 0);
}

// Round 4
// 494.558 us; speedup vs baseline: 1.4034x; 1.0368x over previous
//
#include <hip/hip_runtime.h>

typedef __attribute__((ext_vector_type(4))) float f32x4;
typedef __attribute__((ext_vector_type(8))) short short8;
typedef __attribute__((ext_vector_type(4))) unsigned short u16x4;
typedef __attribute__((ext_vector_type(8))) unsigned short u16x8;

#define MFMA(a, b, c) __builtin_amdgcn_mfma_f32_16x16x32_bf16(a, b, c, 0, 0, 0)
#define GLOAD16(g, l) __builtin_amdgcn_global_load_lds( \
    (const __attribute__((address_space(1))) unsigned int*)(g), \
    (__attribute__((address_space(3))) unsigned int*)(l), 16, 0, 0)

#define BARX() __builtin_amdgcn_s_barrier()
#define LGK0() asm volatile("s_waitcnt lgkmcnt(0)" ::: "memory")
#define VM6 asm volatile("s_waitcnt vmcnt(6)" ::: "memory")
#define VM4 asm volatile("s_waitcnt vmcnt(4)" ::: "memory")
#define VM0 asm volatile("s_waitcnt vmcnt(0)" ::: "memory")
#define NOWAIT ((void)0)

__device__ inline unsigned short f2bf(float f) {
    unsigned int u = __float_as_uint(f);
    u += 0x7fffu + ((u >> 16) & 1u);   // RNE
    return (unsigned short)(u >> 16);
}

// ---------------------------------------------------------------------------
__global__ __launch_bounds__(256) void cvt_kernel(const float* __restrict__ in,
                                                  unsigned short* __restrict__ out, int n4,
                                                  float scale) {
    int i = blockIdx.x * 256 + threadIdx.x;
    if (i < n4) {
        f32x4 v = *(const f32x4*)(in + (long long)i * 4);
        u16x4 o;
#pragma unroll
        for (int j = 0; j < 4; j++) o[j] = f2bf(v[j] * scale);
        *(u16x4*)&out[(long long)i * 4] = o;
    }
}

// bias concat for fused QK: out[0:1024] = bq/32, out[1024:2048] = bk
__global__ __launch_bounds__(256) void biascat_kernel(const float* __restrict__ bq,
                                                      const float* __restrict__ bk,
                                                      float* __restrict__ out) {
    int i = blockIdx.x * 256 + threadIdx.x;
    if (i < 1024) out[i] = bq[i] * 0.03125f;
    else if (i < 2048) out[i] = bk[i - 1024];
}

// ---------------------------------------------------------------------------
__global__ __launch_bounds__(256) void ln_kernel(const float* __restrict__ x,
                                                 const float* __restrict__ g,
                                                 const float* __restrict__ be,
                                                 unsigned short* __restrict__ out) {
    const int row = blockIdx.x, tid = threadIdx.x;
    const float* px = x + (long long)row * 1024;
    f32x4 v = *(const f32x4*)(px + tid * 4);
    float s = v[0] + v[1] + v[2] + v[3];
    float q = v[0] * v[0] + v[1] * v[1] + v[2] * v[2] + v[3] * v[3];
#pragma unroll
    for (int o = 32; o; o >>= 1) { s += __shfl_xor(s, o); q += __shfl_xor(q, o); }
    __shared__ float sm[10];
    const int lane = tid & 63, wid = tid >> 6;
    if (lane == 0) { sm[wid] = s; sm[4 + wid] = q; }
    __syncthreads();
    if (tid == 0) {
        float ts = sm[0] + sm[1] + sm[2] + sm[3];
        float tq = sm[4] + sm[5] + sm[6] + sm[7];
        float mean = ts * (1.f / 1024.f);
        float var = tq * (1.f / 1024.f) - mean * mean;
        sm[8] = mean; sm[9] = rsqrtf(var + 1e-5f);
    }
    __syncthreads();
    float mean = sm[8], rs = sm[9];
    f32x4 gg = *(const f32x4*)(g + tid * 4);
    f32x4 bb = *(const f32x4*)(be + tid * 4);
    u16x4 o;
#pragma unroll
    for (int i = 0; i < 4; i++) o[i] = f2bf((v[i] - mean) * rs * gg[i] + bb[i]);
    *(u16x4*)&out[(long long)row * 1024 + tid * 4] = o;
}

// ---------------------------------------------------------------------------
// Causal softmax over row [0..t], writes bf16 probs IN-PLACE over the fp32 row.
__global__ __launch_bounds__(256) void softmax_kernel(float* __restrict__ S) {
    const int T = 2048;
    const int t = blockIdx.x, b = blockIdx.y, tid = threadIdx.x;
    float* row = S + ((long long)b * T + t) * T;
    const int base = tid * 8;
    f32x4 v0 = *(const f32x4*)(row + base);
    f32x4 v1 = *(const f32x4*)(row + base + 4);
    float mx = -1e30f;
#pragma unroll
    for (int i = 0; i < 4; i++) {
        if (base + i <= t)     mx = fmaxf(mx, v0[i]);
        if (base + 4 + i <= t) mx = fmaxf(mx, v1[i]);
    }
#pragma unroll
    for (int o = 32; o; o >>= 1) mx = fmaxf(mx, __shfl_xor(mx, o));
    __shared__ float sm[10];
    const int lane = tid & 63, wid = tid >> 6;
    if (lane == 0) sm[wid] = mx;
    __syncthreads();
    if (tid == 0) sm[8] = fmaxf(fmaxf(sm[0], sm[1]), fmaxf(sm[2], sm[3]));
    __syncthreads();
    float M = sm[8];
    float e[8]; float s = 0.f;
#pragma unroll
    for (int i = 0; i < 4; i++) {
        e[i]     = (base + i <= t)     ? __expf(v0[i] - M) : 0.f;
        e[4 + i] = (base + 4 + i <= t) ? __expf(v1[i] - M) : 0.f;
        s += e[i] + e[4 + i];
    }
#pragma unroll
    for (int o = 32; o; o >>= 1) s += __shfl_xor(s, o);
    if (lane == 0) sm[4 + wid] = s;
    __syncthreads();
    if (tid == 0) sm[9] = 1.f / (sm[4] + sm[5] + sm[6] + sm[7]);
    __syncthreads();
    float inv = sm[9];
    unsigned short* P = (unsigned short*)row;
    u16x8 o;
#pragma unroll
    for (int i = 0; i < 8; i++) o[i] = f2bf(e[i] * inv);
    *(u16x8*)&P[base] = o;
}

// ---------------------------------------------------------------------------
// Shared epilogue for both GEMM geometries
#define EPILOGUE(FM_COUNT) do {                                                     \
    const int cc = lane & 15, rr = (lane >> 4) * 4;                                 \
    _Pragma("unroll")                                                               \
    for (int fm = 0; fm < FM_COUNT; fm++)                                           \
        _Pragma("unroll")                                                           \
        for (int fn = 0; fn < 4; fn++) {                                            \
            f32x4 av = acc[fm][fn];                                                 \
            int colg = n0 + wn + fn * 16 + cc;                                      \
            int rowg0 = m0 + wm + fm * 16 + rr;                                     \
            float bv = bias ? bias[colg] : 0.f;                                     \
            if (MODE == 3) {                                                        \
                u16x4 o;                                                            \
                _Pragma("unroll")                                                   \
                for (int i = 0; i < 4; i++) o[i] = f2bf((av[i] + bv) * scale);      \
                *(u16x4*)&outb[(long long)colg * ldo + rowg0] = o;                  \
            } else {                                                                \
                _Pragma("unroll")                                                   \
                for (int i = 0; i < 4; i++) {                                       \
                    float v = av[i] + bv;                                           \
                    long long idx = (long long)(rowg0 + i) * ldo + colg;            \
                    if (MODE == 0) outf[idx] = v;                                   \
                    if (MODE == 1) outf[idx] = v + resid[idx];                      \
                    if (MODE == 2) outb[idx] = f2bf(v * scale);                     \
                    if (MODE == 4) { outf[idx] = v; outb[idx] = f2bf(v); }          \
                    if (MODE == 5) outb[idx] = f2bf(0.5f * v * (1.f + erff(v * 0.70710678f))); \
                }                                                                   \
            }                                                                       \
        }                                                                           \
} while (0)

// ---------------------------------------------------------------------------
// GEOM B: 256x128 tile, BK=64, 8 waves 4Mx2N (per-wave 64x64 = 4x4 frags).
// Triple-buffered (144 KB), prefetch depth 2, vmcnt(6) counted.
// 2 phases per K-tile, 16 MFMA per phase.
#define TILE_B(CB, PB, KPRE, PF, WAITER) do {                                       \
    const unsigned short* Lc = LDS + (CB) * 24576;                                  \
    unsigned short* Lp = LDS + (PB) * 24576;                                        \
    short8 Af[4], Bf[4];                                                            \
    _Pragma("unroll") for (int i = 0; i < 4; i++)                                   \
        Af[i] = *(const short8*)(Lc + ao[i] + ks0);                                 \
    _Pragma("unroll") for (int j = 0; j < 4; j++)                                   \
        Bf[j] = *(const short8*)(Lc + bo[j] + ks0);                                 \
    if (PF) { GLOAD16(srcA[0] + (KPRE), Lp + dstA[0]);                              \
              GLOAD16(srcA[1] + (KPRE), Lp + dstA[1]);                              \
              GLOAD16(srcA[2] + (KPRE), Lp + dstA[2]); }                            \
    BARX(); LGK0();                                                                 \
    __builtin_amdgcn_s_setprio(1);                                                  \
    _Pragma("unroll") for (int i = 0; i < 4; i++)                                   \
        _Pragma("unroll") for (int j = 0; j < 4; j++)                               \
            acc[i][j] = MFMA(Af[i], Bf[j], acc[i][j]);                              \
    __builtin_amdgcn_s_setprio(0); BARX();                                          \
    _Pragma("unroll") for (int i = 0; i < 4; i++)                                   \
        Af[i] = *(const short8*)(Lc + ao[i] + ks1);                                 \
    _Pragma("unroll") for (int j = 0; j < 4; j++)                                   \
        Bf[j] = *(const short8*)(Lc + bo[j] + ks1);                                 \
    if (PF) { GLOAD16(srcA[3] + (KPRE), Lp + dstA[3]);                              \
              GLOAD16(srcB[0] + (KPRE), Lp + dstB[0]);                              \
              GLOAD16(srcB[1] + (KPRE), Lp + dstB[1]); }                            \
    WAITER;                                                                         \
    BARX(); LGK0();                                                                 \
    __builtin_amdgcn_s_setprio(1);                                                  \
    _Pragma("unroll") for (int i = 0; i < 4; i++)                                   \
        _Pragma("unroll") for (int j = 0; j < 4; j++)                               \
            acc[i][j] = MFMA(Af[i], Bf[j], acc[i][j]);                              \
    __builtin_amdgcn_s_setprio(0); BARX();                                          \
} while (0)

template <int MODE>
__global__ __launch_bounds__(512, 2) void gemm_bt(
    const unsigned short* __restrict__ A, int lda, long long sA,
    const unsigned short* __restrict__ Bw, int ldb, long long sB,
    const float* __restrict__ bias,
    const float* __restrict__ resid, long long sR,
    float* __restrict__ outf, unsigned short* __restrict__ outb,
    int ldo, long long sO, int K, float scale, int flags) {
    const int m0 = blockIdx.y * 256, n0 = blockIdx.x * 128;
    if ((flags & 1) && n0 >= m0 + 256) return;
    const int bz = blockIdx.z;
    A += (long long)bz * sA; Bw += (long long)bz * sB;
    if (resid) resid += (long long)bz * sR;
    if (outf) outf += (long long)bz * sO;
    if (outb) outb += (long long)bz * sO;
    const int Keff = (flags & 2) ? (m0 + 256 < K ? m0 + 256 : K) : K;
    const int nt = Keff >> 6;

    __shared__ __align__(16) unsigned short LDS[3 * 24576];   // 144 KB

    const int tid = threadIdx.x, lane = tid & 63, wid = tid >> 6;

    const unsigned short* srcA[4]; int dstA[4];
    const unsigned short* srcB[2]; int dstB[2];
#pragma unroll
    for (int g = 0; g < 4; g++) {
        int p = g * 512 + wid * 64 + lane;
        int r = p >> 3, cs = (p & 7) ^ (r & 7);
        srcA[g] = A + (long long)(m0 + r) * lda + cs * 8;
        dstA[g] = g * 4096 + wid * 512;
    }
#pragma unroll
    for (int g = 0; g < 2; g++) {
        int p = g * 512 + wid * 64 + lane;
        int r = p >> 3, cs = (p & 7) ^ (r & 7);
        srcB[g] = Bw + (long long)(n0 + r) * ldb + cs * 8;
        dstB[g] = 16384 + g * 4096 + wid * 512;
    }

    const int wm = (wid >> 1) * 64, wn = (wid & 1) * 64;
    const int fr = lane & 15;
    int ao[4], bo[4];
#pragma unroll
    for (int i = 0; i < 4; i++) ao[i] = (wm + i * 16 + fr) * 64;
#pragma unroll
    for (int j = 0; j < 4; j++) bo[j] = 16384 + (wn + j * 16 + fr) * 64;
    const int ks0 = (((lane >> 4)) ^ (fr & 7)) * 8;
    const int ks1 = ((4 + (lane >> 4)) ^ (fr & 7)) * 8;

    f32x4 acc[4][4] = {};

#pragma unroll
    for (int g = 0; g < 4; g++) GLOAD16(srcA[g], LDS + dstA[g]);
#pragma unroll
    for (int g = 0; g < 2; g++) GLOAD16(srcB[g], LDS + dstB[g]);
#pragma unroll
    for (int g = 0; g < 4; g++) GLOAD16(srcA[g] + 64, LDS + 24576 + dstA[g]);
#pragma unroll
    for (int g = 0; g < 2; g++) GLOAD16(srcB[g] + 64, LDS + 24576 + dstB[g]);
    VM6; BARX();
    __builtin_amdgcn_sched_barrier(0);

    int c = 0, p = 2, kpre = 128;
    for (int t = 0; t < nt - 2; ++t) {
        TILE_B(c, p, kpre, true, VM6);
        c = (c == 2) ? 0 : c + 1;
        p = (p == 2) ? 0 : p + 1;
        kpre += 64;
    }
    TILE_B(c, p, 0, false, VM0);
    c = (c == 2) ? 0 : c + 1;
    TILE_B(c, p, 0, false, NOWAIT);

    EPILOGUE(4);
}

// ---------------------------------------------------------------------------
// GEOM A (m201-like): 256x256 tile, BK=32, 8 waves 2Mx4N (per-wave 128x64 =
// 8x4 frags, 0.375 LDS-reads/MFMA). Triple-buffered (96 KB), vmcnt(4) counted.
// 2 phases per K-tile, 16 MFMA per phase. Swizzle: chunk ^= (row>>1)&3.
#define TILE_A(CB, PB, KPRE, PF, WAITER) do {                                       \
    const unsigned short* Lc = LDS + (CB) * 16384;                                  \
    unsigned short* Lp = LDS + (PB) * 16384;                                        \
    short8 Af[4], Bf[4];                                                            \
    _Pragma("unroll") for (int i = 0; i < 4; i++)                                   \
        Af[i] = *(const short8*)(Lc + aoW[i] + ksW);                                \
    _Pragma("unroll") for (int j = 0; j < 4; j++)                                   \
        Bf[j] = *(const short8*)(Lc + boW[j] + ksW);                                \
    if (PF) { GLOAD16(srcA[0] + (KPRE), Lp + dstA[0]);                              \
              GLOAD16(srcB[0] + (KPRE), Lp + dstB[0]); }                            \
    BARX(); LGK0();                                                                 \
    __builtin_amdgcn_s_setprio(1);                                                  \
    _Pragma("unroll") for (int i = 0; i < 4; i++)                                   \
        _Pragma("unroll") for (int j = 0; j < 4; j++)                               \
            acc[i][j] = MFMA(Af[i], Bf[j], acc[i][j]);                              \
    __builtin_amdgcn_s_setprio(0); BARX();                                          \
    _Pragma("unroll") for (int i = 0; i < 4; i++)                                   \
        Af[i] = *(const short8*)(Lc + aoW[4 + i] + ksW);                            \
    if (PF) { GLOAD16(srcA[1] + (KPRE), Lp + dstA[1]);                              \
              GLOAD16(srcB[1] + (KPRE), Lp + dstB[1]); }                            \
    WAITER;                                                                         \
    BARX(); LGK0();                                                                 \
    __builtin_amdgcn_s_setprio(1);                                                  \
    _Pragma("unroll") for (int i = 0; i < 4; i++)                                   \
        _Pragma("unroll") for (int j = 0; j < 4; j++)                               \
            acc[4 + i][j] = MFMA(Af[i], Bf[j], acc[4 + i][j]);                      \
    __builtin_amdgcn_s_setprio(0); BARX();                                          \
} while (0)

template <int MODE>
__global__ __launch_bounds__(512, 2) void gemm_wide(
    const unsigned short* __restrict__ A, int lda, long long sA,
    const unsigned short* __restrict__ Bw, int ldb, long long sB,
    const float* __restrict__ bias,
    const float* __restrict__ resid, long long sR,
    float* __restrict__ outf, unsigned short* __restrict__ outb,
    int ldo, long long sO, int K, float scale, int flags) {
    const int m0 = blockIdx.y * 256, n0 = blockIdx.x * 256;
    if ((flags & 1) && n0 > m0) return;
    const int bz = blockIdx.z;
    A += (long long)bz * sA; Bw += (long long)bz * sB;
    if (resid) resid += (long long)bz * sR;
    if (outf) outf += (long long)bz * sO;
    if (outb) outb += (long long)bz * sO;
    const int nt = K >> 5;

    __shared__ __align__(16) unsigned short LDS[3 * 16384];   // 96 KB

    const int tid = threadIdx.x, lane = tid & 63, wid = tid >> 6;

    const unsigned short* srcA[2]; int dstA[2];
    const unsigned short* srcB[2]; int dstB[2];
#pragma unroll
    for (int g = 0; g < 2; g++) {
        int p = g * 512 + wid * 64 + lane;
        int r = p >> 2, cs = (p & 3) ^ ((r >> 1) & 3);
        srcA[g] = A + (long long)(m0 + r) * lda + cs * 8;
        dstA[g] = g * 4096 + wid * 512;
        srcB[g] = Bw + (long long)(n0 + r) * ldb + cs * 8;
        dstB[g] = 8192 + g * 4096 + wid * 512;
    }

    const int wm = (wid >> 2) * 128, wn = (wid & 3) * 64;
    const int fr = lane & 15;
    int aoW[8], boW[4];
#pragma unroll
    for (int i = 0; i < 8; i++) aoW[i] = (wm + i * 16 + fr) * 32;
#pragma unroll
    for (int j = 0; j < 4; j++) boW[j] = 8192 + (wn + j * 16 + fr) * 32;
    const int ksW = ((lane >> 4) ^ ((fr >> 1) & 3)) * 8;

    f32x4 acc[8][4] = {};

#pragma unroll
    for (int g = 0; g < 2; g++) { GLOAD16(srcA[g], LDS + dstA[g]);
                                  GLOAD16(srcB[g], LDS + dstB[g]); }
#pragma unroll
    for (int g = 0; g < 2; g++) { GLOAD16(srcA[g] + 32, LDS + 16384 + dstA[g]);
                                  GLOAD16(srcB[g] + 32, LDS + 16384 + dstB[g]); }
    VM4; BARX();
    __builtin_amdgcn_sched_barrier(0);

    int c = 0, p = 2, kpre = 64;
    for (int t = 0; t < nt - 2; ++t) {
        TILE_A(c, p, kpre, true, VM4);
        c = (c == 2) ? 0 : c + 1;
        p = (p == 2) ? 0 : p + 1;
        kpre += 32;
    }
    TILE_A(c, p, 0, false, VM0);
    c = (c == 2) ? 0 : c + 1;
    TILE_A(c, p, 0, false, NOWAIT);

    EPILOGUE(8);
}

// ---------------------------------------------------------------------------
extern "C" void kernel_launch(void* const* d_in, const int* in_sizes, int n_in,
                              void* d_out, int out_size, void* d_ws, size_t ws_size,
                              hipStream_t stream) {
    const float* x      = (const float*)d_in[0];
    const float* g1     = (const float*)d_in[1];
    const float* be1    = (const float*)d_in[2];
    const float* b_lin1 = (const float*)d_in[4];
    const float* bq     = (const float*)d_in[6];
    const float* bk     = (const float*)d_in[8];
    const float* bv     = (const float*)d_in[10];
    const float* b_lin2 = (const float*)d_in[12];
    const float* g2     = (const float*)d_in[13];
    const float* be2    = (const float*)d_in[14];
    const float* b_ff1  = (const float*)d_in[16];
    const float* b_ff2  = (const float*)d_in[18];

    const long long MB = 1024LL * 1024LL;
    char* ws = (char*)d_ws;
    unsigned short* xn1 = (unsigned short*)(ws + 0);        // 16MB, dead after lin1
    unsigned short* x1b = (unsigned short*)(ws + 16 * MB);  // 16MB, dead after QKV
    float*          S   = (float*)(ws + 0);                 // 64MB, scores->probs
    float*          bqk = (float*)(ws + 60 * MB);           // 8KB, dead after QK gemm
    float*          x1f = (float*)(ws + 64 * MB);           // 32MB, resid for lin2
    unsigned short* xn2 = (unsigned short*)(ws + 64 * MB);  // reuses x1f after LN2
    unsigned short* qk  = (unsigned short*)(ws + 96 * MB);  // 32MB [8192,2048] Q||K
    unsigned short* vT  = (unsigned short*)(ws + 128 * MB); // 16MB transposed V
    unsigned short* attn= (unsigned short*)(ws + 96 * MB);  // reuses qk after scores
    unsigned short* h   = (unsigned short*)(ws + 96 * MB);  // 32MB, after lin2
    float*          x2  = (float*)(ws + 144 * MB);          // 32MB
    unsigned short* wb1 = (unsigned short*)(ws + 176 * MB);
    unsigned short* wbq = (unsigned short*)(ws + 178 * MB); // wbq+wbk contiguous =
    unsigned short* wbk = (unsigned short*)(ws + 180 * MB); //   combined [2048,1024]
    unsigned short* wbv = (unsigned short*)(ws + 182 * MB);
    unsigned short* wb2 = (unsigned short*)(ws + 184 * MB);
    unsigned short* wbf1= (unsigned short*)(ws + 186 * MB); // 4MB
    unsigned short* wbf2= (unsigned short*)(ws + 190 * MB); // 4MB

    auto cvt = [&](const void* src, unsigned short* dst, long long n, float sc) {
        int n4 = (int)(n / 4);
        cvt_kernel<<<(n4 + 255) / 256, 256, 0, stream>>>((const float*)src, dst, n4, sc);
    };
    cvt(d_in[3], wb1, 1048576, 1.f);
    cvt(d_in[5], wbq, 1048576, 0.03125f);   // fold 1/sqrt(D) into Q weights
    cvt(d_in[7], wbk, 1048576, 1.f);
    cvt(d_in[9], wbv, 1048576, 1.f);
    cvt(d_in[11], wb2, 1048576, 1.f);
    cvt(d_in[15], wbf1, 2097152, 1.f);
    cvt(d_in[17], wbf2, 2097152, 1.f);
    biascat_kernel<<<8, 256, 0, stream>>>(bq, bk, bqk);

    // LN1
    ln_kernel<<<8192, 256, 0, stream>>>(x, g1, be1, xn1);
    // lin1: fp32 (residual base) + bf16
    gemm_bt<4><<<dim3(8, 32, 1), 512, 0, stream>>>(xn1, 1024, 0, wb1, 1024, 0, b_lin1,
        nullptr, 0, x1f, x1b, 1024, 0, 1024, 1.f, 0);
    // fused Q||K -> qk [8192, 2048] (Q pre-scaled by 1/32)
    gemm_wide<2><<<dim3(8, 32, 1), 512, 0, stream>>>(x1b, 1024, 0, wbq, 1024, 0, bqk,
        nullptr, 0, nullptr, qk, 2048, 0, 1024, 1.f, 0);
    // V, transposed per batch: vT[b][d][t]
    gemm_bt<3><<<dim3(8, 8, 4), 512, 0, stream>>>(x1b, 1024, 2048LL * 1024, wbv, 1024, 0, bv,
        nullptr, 0, nullptr, vT, 2048, 2097152LL, 1024, 1.f, 0);
    // scores (causal blocks only), fp32: A = Q cols, B = K cols of qk
    gemm_wide<0><<<dim3(8, 8, 4), 512, 0, stream>>>(qk, 2048, 4194304LL, qk + 1024, 2048, 4194304LL,
        nullptr, nullptr, 0, S, nullptr, 2048, 4194304LL, 1024, 1.f, 1);
    // softmax -> bf16 probs in place
    softmax_kernel<<<dim3(2048, 4), 256, 0, stream>>>(S);
    // PV: attn = P @ V  (A = bf16 probs with row stride 4096, B = vT), K-limit
    gemm_bt<2><<<dim3(8, 8, 4), 512, 0, stream>>>((unsigned short*)S, 4096, 8388608LL,
        vT, 2048, 2097152LL, nullptr, nullptr, 0, nullptr, attn, 1024, 2097152LL, 2048, 1.f, 2);
    // lin2 + residual(x1f) -> x2 fp32
    gemm_bt<1><<<dim3(8, 32, 1), 512, 0, stream>>>(attn, 1024, 0, wb2, 1024, 0, b_lin2,
        x1f, 0, x2, nullptr, 1024, 0, 1024, 1.f, 0);
    // LN2
    ln_kernel<<<8192, 256, 0, stream>>>(x2, g2, be2, xn2);
    // FFN1 + exact GELU -> h bf16 [8192,2048]
    gemm_wide<5><<<dim3(8, 32, 1), 512, 0, stream>>>(xn2, 1024, 0, wbf1, 1024, 0, b_ff1,
        nullptr, 0, nullptr, h, 2048, 0, 1024, 1.f, 0);
    // FFN2 + residual(x2) -> d_out fp32
    gemm_bt<1><<<dim3(8, 32, 1), 512, 0, stream>>>(h, 2048, 0, wbf2, 2048, 0, b_ff2,
        x2, 0, (float*)d_out, nullptr, 1024, 0, 2048, 1.f, 0);
}